// Round 8
// baseline (675.121 us; speedup 1.0000x reference)
//
#include <hip/hip_runtime.h>

#define NN 50000
#define NE 800000
#define GPW 2   // nodes per wave: R7 showed 4x starves TLP (12.5k waves), 1x wastes
                // per-wave overhead; 2x keeps 25k waves (~3x oversubscription)

// ---- bf16 helpers ----
__device__ __forceinline__ float bf2f(unsigned short u) {
    union { unsigned int i; float f; } v; v.i = ((unsigned int)u) << 16; return v.f;
}
__device__ __forceinline__ unsigned short f2bf(float f) {
    union { float f; unsigned int i; } v; v.f = f;
    unsigned int r = v.i + 0x7fffu + ((v.i >> 16) & 1u);   // round-to-nearest-even
    return (unsigned short)(r >> 16);
}
// packed u32 of 2 bf16 -> two f32 (2 VALU ops)
__device__ __forceinline__ void bfp2(unsigned v, float& lo, float& hi) {
    lo = __uint_as_float(v << 16);
    hi = __uint_as_float(v & 0xffff0000u);
}
__device__ __forceinline__ float rdlane_f(float x, int l) {
    return __uint_as_float(__builtin_amdgcn_readlane(__float_as_uint(x), l));
}

// ---------------- CSR build ----------------

__global__ void k_count(const int* __restrict__ dst, int* __restrict__ cnt, int E) {
    int e = blockIdx.x * 256 + threadIdx.x;
    if (e < E) atomicAdd(&cnt[dst[e]], 1);
}

__global__ void k_dinv(const int* __restrict__ cnt, float* __restrict__ dinv, int N) {
    int i = blockIdx.x * 256 + threadIdx.x;
    if (i < N) dinv[i] = rsqrtf(2.0f + (float)cnt[i]);
}

__global__ void k_scanA(const int* __restrict__ cnt, int* __restrict__ row_ptr,
                        int* __restrict__ bsum, int N) {
    __shared__ int buf[256];
    int i = blockIdx.x * 256 + threadIdx.x;
    int v = (i < N) ? cnt[i] : 0;
    buf[threadIdx.x] = v;
    __syncthreads();
    for (int off = 1; off < 256; off <<= 1) {
        int t = (threadIdx.x >= off) ? buf[threadIdx.x - off] : 0;
        __syncthreads();
        buf[threadIdx.x] += t;
        __syncthreads();
    }
    if (i < N) row_ptr[i] = buf[threadIdx.x] - v;
    if (threadIdx.x == 255) bsum[blockIdx.x] = buf[255];
}

__global__ void k_scanB(int* __restrict__ bsum, int nb) {
    __shared__ int buf[256];
    int v = (threadIdx.x < nb) ? bsum[threadIdx.x] : 0;
    buf[threadIdx.x] = v;
    __syncthreads();
    for (int off = 1; off < 256; off <<= 1) {
        int t = (threadIdx.x >= off) ? buf[threadIdx.x - off] : 0;
        __syncthreads();
        buf[threadIdx.x] += t;
        __syncthreads();
    }
    if (threadIdx.x < nb) bsum[threadIdx.x] = buf[threadIdx.x] - v;
}

__global__ void k_scanC(int* __restrict__ row_ptr, const int* __restrict__ bsum,
                        int N, int E) {
    int i = blockIdx.x * 256 + threadIdx.x;
    if (i < N) row_ptr[i] += bsum[blockIdx.x];
    if (i == 0) row_ptr[N] = E;
}

__global__ void k_fill(const int* __restrict__ src, const int* __restrict__ dst,
                       const float* __restrict__ dinv, const int* __restrict__ row_ptr,
                       int* __restrict__ cursor, int2* __restrict__ csr, int E) {
    int e = blockIdx.x * 256 + threadIdx.x;
    if (e >= E) return;
    int s = src[e], d = dst[e];
    int pos = row_ptr[d] + atomicAdd(&cursor[d], 1);
    float nm = dinv[s] * dinv[d];
    csr[pos] = make_int2(s, __float_as_int(nm));
}

// ---------------- GEMM layer 1: H = X @ W1 -> bf16 H ----------------
// #pragma unroll 1: full unroll spills ~230MB scratch (R1).

__global__ __launch_bounds__(256, 4) void k_gemm128(const float* __restrict__ X,
                                                    const float* __restrict__ W,
                                                    unsigned short* __restrict__ H, int N) {
    const int K = 128;
    __shared__ float Ws[K * 64];
    for (int i = threadIdx.x; i < K * 16; i += 256)
        ((float4*)Ws)[i] = ((const float4*)W)[i];
    __syncthreads();

    const int g  = threadIdx.x >> 3;
    const int c0 = (threadIdx.x & 7) * 8;
    const int r0 = blockIdx.x * 64 + g * 2;
    const int r1 = r0 + 1;
    const bool v0 = r0 < N, v1 = r1 < N;

    float a00=0,a01=0,a02=0,a03=0,a04=0,a05=0,a06=0,a07=0;
    float a10=0,a11=0,a12=0,a13=0,a14=0,a15=0,a16=0,a17=0;

    const float* x0 = X + (size_t)r0 * K;
    const float* x1 = X + (size_t)r1 * K;

#pragma unroll 1
    for (int k0 = 0; k0 < K; k0 += 4) {
        float4 xa = v0 ? *(const float4*)(x0 + k0) : make_float4(0, 0, 0, 0);
        float4 xb = v1 ? *(const float4*)(x1 + k0) : make_float4(0, 0, 0, 0);
#pragma unroll
        for (int kk = 0; kk < 4; ++kk) {
            const float xs0 = (kk == 0) ? xa.x : (kk == 1) ? xa.y : (kk == 2) ? xa.z : xa.w;
            const float xs1 = (kk == 0) ? xb.x : (kk == 1) ? xb.y : (kk == 2) ? xb.z : xb.w;
            const float* wr = &Ws[(k0 + kk) * 64 + c0];
            const float4 w0 = *(const float4*)(wr);
            const float4 w1 = *(const float4*)(wr + 4);
            a00 = fmaf(xs0, w0.x, a00); a01 = fmaf(xs0, w0.y, a01);
            a02 = fmaf(xs0, w0.z, a02); a03 = fmaf(xs0, w0.w, a03);
            a04 = fmaf(xs0, w1.x, a04); a05 = fmaf(xs0, w1.y, a05);
            a06 = fmaf(xs0, w1.z, a06); a07 = fmaf(xs0, w1.w, a07);
            a10 = fmaf(xs1, w0.x, a10); a11 = fmaf(xs1, w0.y, a11);
            a12 = fmaf(xs1, w0.z, a12); a13 = fmaf(xs1, w0.w, a13);
            a14 = fmaf(xs1, w1.x, a14); a15 = fmaf(xs1, w1.y, a15);
            a16 = fmaf(xs1, w1.z, a16); a17 = fmaf(xs1, w1.w, a17);
        }
    }

    if (v0) {
        uint4 p;
        p.x = (unsigned)f2bf(a00) | ((unsigned)f2bf(a01) << 16);
        p.y = (unsigned)f2bf(a02) | ((unsigned)f2bf(a03) << 16);
        p.z = (unsigned)f2bf(a04) | ((unsigned)f2bf(a05) << 16);
        p.w = (unsigned)f2bf(a06) | ((unsigned)f2bf(a07) << 16);
        *(uint4*)&H[(size_t)r0 * 64 + c0] = p;
    }
    if (v1) {
        uint4 p;
        p.x = (unsigned)f2bf(a10) | ((unsigned)f2bf(a11) << 16);
        p.y = (unsigned)f2bf(a12) | ((unsigned)f2bf(a13) << 16);
        p.z = (unsigned)f2bf(a14) | ((unsigned)f2bf(a15) << 16);
        p.w = (unsigned)f2bf(a16) | ((unsigned)f2bf(a17) << 16);
        *(uint4*)&H[(size_t)r1 * 64 + c0] = p;
    }
}

// ---------------- Aggregation (bf16 H, 8 edge-slots x 8 ch/lane) ----------------
// R7 model (validated): T = (waves/CU / resident) x wave_latency.
// This round: GPW=2 (25k waves) + 8-edge gathers (uint4 = 8 bf16/lane):
// one VMEM instr covers 8 edge-rows, halving t-iters and bpermutes/node.
// Lane layout: g = lane>>3 (8 edge slots), c8 = (lane&7)*8 (8 channels).
// After 3-step xor-reduce (8,16,32) every lane holds full sums for its 8 ch.

template <bool RELU>
__device__ __forceinline__ void agg_node8(const unsigned short* __restrict__ H,
                                          const long long* __restrict__ csr_ll,
                                          const float* __restrict__ bias, float di,
                                          int i, int s, int e,
                                          int lane, int g, int c8, float r[8]) {
    float a0=0,a1=0,a2=0,a3=0,a4=0,a5=0,a6=0,a7=0;

    for (int base = s; base < e; base += 64) {
        int eidx = base + lane;
        long long pk = (eidx < e) ? csr_ll[eidx] : 0LL;
        int px = (int)(pk & 0xffffffffLL);
        int py = (int)(pk >> 32);                 // norm bits (0 -> 0.0f)
        int m  = e - base; if (m > 64) m = 64;
        int nt = (m + 7) >> 3;
#pragma unroll 4
        for (int t = 0; t < nt; ++t) {
            int sl   = t * 8 + g;
            int ss   = __shfl(px, sl);
            float nn = __uint_as_float(__shfl(py, sl));
            uint4 hv = *(const uint4*)&H[(size_t)ss * 64 + c8];
            float l0,h0,l1,h1,l2,h2,l3,h3;
            bfp2(hv.x, l0, h0); bfp2(hv.y, l1, h1);
            bfp2(hv.z, l2, h2); bfp2(hv.w, l3, h3);
            a0 = fmaf(l0, nn, a0); a1 = fmaf(h0, nn, a1);
            a2 = fmaf(l1, nn, a2); a3 = fmaf(h1, nn, a3);
            a4 = fmaf(l2, nn, a4); a5 = fmaf(h2, nn, a5);
            a6 = fmaf(l3, nn, a6); a7 = fmaf(h3, nn, a7);
        }
    }

    // reduce the 8 edge-slot groups (lane bits 3,4,5)
#pragma unroll
    for (int d = 8; d <= 32; d <<= 1) {
        a0 += __shfl_xor(a0, d); a1 += __shfl_xor(a1, d);
        a2 += __shfl_xor(a2, d); a3 += __shfl_xor(a3, d);
        a4 += __shfl_xor(a4, d); a5 += __shfl_xor(a5, d);
        a6 += __shfl_xor(a6, d); a7 += __shfl_xor(a7, d);
    }

    float sl2 = 2.0f * di * di;
    uint4 hv = *(const uint4*)&H[(size_t)i * 64 + c8];
    float l0,h0,l1,h1,l2,h2,l3,h3;
    bfp2(hv.x, l0, h0); bfp2(hv.y, l1, h1);
    bfp2(hv.z, l2, h2); bfp2(hv.w, l3, h3);
    float4 ba = *(const float4*)&bias[c8];
    float4 bb = *(const float4*)&bias[c8 + 4];
    r[0] = a0 + sl2 * l0 + ba.x;  r[1] = a1 + sl2 * h0 + ba.y;
    r[2] = a2 + sl2 * l1 + ba.z;  r[3] = a3 + sl2 * h1 + ba.w;
    r[4] = a4 + sl2 * l2 + bb.x;  r[5] = a5 + sl2 * h2 + bb.y;
    r[6] = a6 + sl2 * l3 + bb.z;  r[7] = a7 + sl2 * h3 + bb.w;
    if (RELU) {
#pragma unroll
        for (int k = 0; k < 8; ++k) r[k] = fmaxf(r[k], 0.f);
    }
}

// Fused: A = ReLU(S*H + b) then y = A @ Wn per node; Hout bf16.
__global__ __launch_bounds__(256, 6) void k_fused(const unsigned short* __restrict__ H,
                                                  const int* __restrict__ row_ptr,
                                                  const long long* __restrict__ csr_ll,
                                                  const float* __restrict__ dinv,
                                                  const float* __restrict__ bias,
                                                  const float* __restrict__ Wn,
                                                  unsigned short* __restrict__ Hout, int N) {
    const int lane = threadIdx.x & 63;
    const int wid  = threadIdx.x >> 6;
    const int i0   = (blockIdx.x * 4 + wid) * GPW;
    if (i0 >= N) return;
    const int g  = lane >> 3;
    const int c8 = (lane & 7) * 8;

    // W column `lane`: compiler sinks these into the tail (R7: VGPR=52, no spill)
    float wreg[64];
#pragma unroll
    for (int k = 0; k < 64; ++k) wreg[k] = Wn[k * 64 + lane];

    int idx = i0 + lane;
    int rp_l   = (lane <= GPW && idx <= NN) ? row_ptr[idx] : 0;
    float di_l = (lane <  GPW && idx <  NN) ? dinv[idx]    : 0.f;

#pragma unroll
    for (int j = 0; j < GPW; ++j) {
        int i = i0 + j;
        if (i >= N) break;
        int   s  = __shfl(rp_l, j);
        int   e  = __shfl(rp_l, j + 1);
        float di = __shfl(di_l, j);

        float r[8];
        agg_node8<true>(H, csr_ll, bias, di, i, s, e, lane, g, c8, r);

        // tail GEMM: channel q*8+k lives in lane q (g=0 group) at r[k]
        float y = 0.0f;
#pragma unroll
        for (int q = 0; q < 8; ++q) {
#pragma unroll
            for (int k = 0; k < 8; ++k)
                y = fmaf(rdlane_f(r[k], q), wreg[q * 8 + k], y);
        }
        Hout[(size_t)i * 64 + lane] = f2bf(y);
    }
}

// Final layer: aggregation only (no ReLU), fp32 out (d_out).
__global__ __launch_bounds__(256, 8) void k_agg_last(const unsigned short* __restrict__ H,
                                                     const int* __restrict__ row_ptr,
                                                     const long long* __restrict__ csr_ll,
                                                     const float* __restrict__ dinv,
                                                     const float* __restrict__ bias,
                                                     float* __restrict__ out, int N) {
    const int lane = threadIdx.x & 63;
    const int wid  = threadIdx.x >> 6;
    const int i0   = (blockIdx.x * 4 + wid) * GPW;
    if (i0 >= N) return;
    const int g  = lane >> 3;
    const int c8 = (lane & 7) * 8;

    int idx = i0 + lane;
    int rp_l   = (lane <= GPW && idx <= NN) ? row_ptr[idx] : 0;
    float di_l = (lane <  GPW && idx <  NN) ? dinv[idx]    : 0.f;

#pragma unroll
    for (int j = 0; j < GPW; ++j) {
        int i = i0 + j;
        if (i >= N) break;
        int   s  = __shfl(rp_l, j);
        int   e  = __shfl(rp_l, j + 1);
        float di = __shfl(di_l, j);

        float r[8];
        agg_node8<false>(H, csr_ll, bias, di, i, s, e, lane, g, c8, r);
        if (g == 0) {   // lanes 0..7 write 2x16B each = 256B contiguous
            *(float4*)&out[(size_t)i * 64 + c8]     = make_float4(r[0], r[1], r[2], r[3]);
            *(float4*)&out[(size_t)i * 64 + c8 + 4] = make_float4(r[4], r[5], r[6], r[7]);
        }
    }
}

// ---------------- launch ----------------

extern "C" void kernel_launch(void* const* d_in, const int* in_sizes, int n_in,
                              void* d_out, int out_size, void* d_ws, size_t ws_size,
                              hipStream_t stream) {
    (void)in_sizes; (void)n_in; (void)out_size; (void)ws_size;

    const float* x  = (const float*)d_in[0];
    const int*   ei = (const int*)d_in[1];
    const float* Wl[5] = {(const float*)d_in[2], (const float*)d_in[4], (const float*)d_in[6],
                          (const float*)d_in[8], (const float*)d_in[10]};
    const float* bl[5] = {(const float*)d_in[3], (const float*)d_in[5], (const float*)d_in[7],
                          (const float*)d_in[9], (const float*)d_in[11]};
    float* out = (float*)d_out;

    const int* src = ei;
    const int* dst = ei + NE;

    char* ws = (char*)d_ws;
    size_t off = 0;
    auto alloc = [&](size_t bytes) -> void* {
        void* p = ws + off;
        off += (bytes + 255) & ~(size_t)255;
        return p;
    };
    int*   cnt      = (int*)alloc(NN * 4);
    int*   row_ptr  = (int*)alloc((NN + 1) * 4);
    int*   cursor   = (int*)alloc(NN * 4);
    int*   bsum     = (int*)alloc(256 * 4);
    float* dinv     = (float*)alloc(NN * 4);
    int2*  csr      = (int2*)alloc((size_t)NE * 8);
    unsigned short* Hb  = (unsigned short*)alloc((size_t)NN * 64 * 2);
    unsigned short* Hb2 = (unsigned short*)alloc((size_t)NN * 64 * 2);

    hipMemsetAsync(cnt, 0, NN * 4, stream);
    hipMemsetAsync(cursor, 0, NN * 4, stream);

    int ebl = (NE + 255) / 256;
    int nbl = (NN + 255) / 256;
    k_count<<<ebl, 256, 0, stream>>>(dst, cnt, NE);
    k_dinv<<<nbl, 256, 0, stream>>>(cnt, dinv, NN);
    k_scanA<<<nbl, 256, 0, stream>>>(cnt, row_ptr, bsum, NN);
    k_scanB<<<1, 256, 0, stream>>>(bsum, nbl);
    k_scanC<<<nbl, 256, 0, stream>>>(row_ptr, bsum, NN, NE);
    k_fill<<<ebl, 256, 0, stream>>>(src, dst, dinv, row_ptr, cursor, csr, NE);

    const long long* csr_ll = (const long long*)csr;
    int gg = (NN + 63) / 64;
    int nwaves = (NN + GPW - 1) / GPW;           // 25000
    int ga = (nwaves + 3) / 4;                   // 6250 blocks

    // layer 1 GEMM (K=128) -> bf16 H
    k_gemm128<<<gg, 256, 0, stream>>>(x, Wl[0], Hb, NN);
    // fused: agg_t (+b_t, ReLU) then @W_{t+1} -> bf16 H
    k_fused<<<ga, 256, 0, stream>>>(Hb,  row_ptr, csr_ll, dinv, bl[0], Wl[1], Hb2, NN);
    k_fused<<<ga, 256, 0, stream>>>(Hb2, row_ptr, csr_ll, dinv, bl[1], Wl[2], Hb,  NN);
    k_fused<<<ga, 256, 0, stream>>>(Hb,  row_ptr, csr_ll, dinv, bl[2], Wl[3], Hb2, NN);
    k_fused<<<ga, 256, 0, stream>>>(Hb2, row_ptr, csr_ll, dinv, bl[3], Wl[4], Hb,  NN);
    // final aggregation (no ReLU) -> fp32 d_out
    k_agg_last<<<ga, 256, 0, stream>>>(Hb, row_ptr, csr_ll, dinv, bl[4], out, NN);
}

// Round 9
// 377.383 us; speedup vs baseline: 1.7890x; 1.7890x over previous
//
#include <hip/hip_runtime.h>

#define NN 50000
#define NE 800000
#define GPW 2   // nodes/wave: R6 (1) = 5.8us/wave, R7 (4) = 12.4us/wave but TLP-starved
                // at 12.5k waves; 2 keeps 25k waves (~3x oversubscription) + 2x amortize

// ---- bf16 helpers ----
__device__ __forceinline__ float bf2f(unsigned short u) {
    union { unsigned int i; float f; } v; v.i = ((unsigned int)u) << 16; return v.f;
}
__device__ __forceinline__ unsigned short f2bf(float f) {
    union { float f; unsigned int i; } v; v.f = f;
    unsigned int r = v.i + 0x7fffu + ((v.i >> 16) & 1u);   // round-to-nearest-even
    return (unsigned short)(r >> 16);
}
__device__ __forceinline__ float rdlane_f(float x, int l) {
    return __uint_as_float(__builtin_amdgcn_readlane(__float_as_uint(x), l));
}

// ---------------- CSR build ----------------

__global__ void k_count(const int* __restrict__ dst, int* __restrict__ cnt, int E) {
    int e = blockIdx.x * 256 + threadIdx.x;
    if (e < E) atomicAdd(&cnt[dst[e]], 1);
}

__global__ void k_dinv(const int* __restrict__ cnt, float* __restrict__ dinv, int N) {
    int i = blockIdx.x * 256 + threadIdx.x;
    if (i < N) dinv[i] = rsqrtf(2.0f + (float)cnt[i]);
}

__global__ void k_scanA(const int* __restrict__ cnt, int* __restrict__ row_ptr,
                        int* __restrict__ bsum, int N) {
    __shared__ int buf[256];
    int i = blockIdx.x * 256 + threadIdx.x;
    int v = (i < N) ? cnt[i] : 0;
    buf[threadIdx.x] = v;
    __syncthreads();
    for (int off = 1; off < 256; off <<= 1) {
        int t = (threadIdx.x >= off) ? buf[threadIdx.x - off] : 0;
        __syncthreads();
        buf[threadIdx.x] += t;
        __syncthreads();
    }
    if (i < N) row_ptr[i] = buf[threadIdx.x] - v;
    if (threadIdx.x == 255) bsum[blockIdx.x] = buf[255];
}

__global__ void k_scanB(int* __restrict__ bsum, int nb) {
    __shared__ int buf[256];
    int v = (threadIdx.x < nb) ? bsum[threadIdx.x] : 0;
    buf[threadIdx.x] = v;
    __syncthreads();
    for (int off = 1; off < 256; off <<= 1) {
        int t = (threadIdx.x >= off) ? buf[threadIdx.x - off] : 0;
        __syncthreads();
        buf[threadIdx.x] += t;
        __syncthreads();
    }
    if (threadIdx.x < nb) bsum[threadIdx.x] = buf[threadIdx.x] - v;
}

__global__ void k_scanC(int* __restrict__ row_ptr, const int* __restrict__ bsum,
                        int N, int E) {
    int i = blockIdx.x * 256 + threadIdx.x;
    if (i < N) row_ptr[i] += bsum[blockIdx.x];
    if (i == 0) row_ptr[N] = E;
}

__global__ void k_fill(const int* __restrict__ src, const int* __restrict__ dst,
                       const float* __restrict__ dinv, const int* __restrict__ row_ptr,
                       int* __restrict__ cursor, int2* __restrict__ csr, int E) {
    int e = blockIdx.x * 256 + threadIdx.x;
    if (e >= E) return;
    int s = src[e], d = dst[e];
    int pos = row_ptr[d] + atomicAdd(&cursor[d], 1);
    float nm = dinv[s] * dinv[d];
    csr[pos] = make_int2(s, __float_as_int(nm));
}

// ---------------- GEMM layer 1: H = X @ W1 -> bf16 H ----------------
// #pragma unroll 1: full unroll spills ~230MB scratch (R1).

__global__ __launch_bounds__(256, 4) void k_gemm128(const float* __restrict__ X,
                                                    const float* __restrict__ W,
                                                    unsigned short* __restrict__ H, int N) {
    const int K = 128;
    __shared__ float Ws[K * 64];
    for (int i = threadIdx.x; i < K * 16; i += 256)
        ((float4*)Ws)[i] = ((const float4*)W)[i];
    __syncthreads();

    const int g  = threadIdx.x >> 3;
    const int c0 = (threadIdx.x & 7) * 8;
    const int r0 = blockIdx.x * 64 + g * 2;
    const int r1 = r0 + 1;
    const bool v0 = r0 < N, v1 = r1 < N;

    float a00=0,a01=0,a02=0,a03=0,a04=0,a05=0,a06=0,a07=0;
    float a10=0,a11=0,a12=0,a13=0,a14=0,a15=0,a16=0,a17=0;

    const float* x0 = X + (size_t)r0 * K;
    const float* x1 = X + (size_t)r1 * K;

#pragma unroll 1
    for (int k0 = 0; k0 < K; k0 += 4) {
        float4 xa = v0 ? *(const float4*)(x0 + k0) : make_float4(0, 0, 0, 0);
        float4 xb = v1 ? *(const float4*)(x1 + k0) : make_float4(0, 0, 0, 0);
#pragma unroll
        for (int kk = 0; kk < 4; ++kk) {
            const float xs0 = (kk == 0) ? xa.x : (kk == 1) ? xa.y : (kk == 2) ? xa.z : xa.w;
            const float xs1 = (kk == 0) ? xb.x : (kk == 1) ? xb.y : (kk == 2) ? xb.z : xb.w;
            const float* wr = &Ws[(k0 + kk) * 64 + c0];
            const float4 w0 = *(const float4*)(wr);
            const float4 w1 = *(const float4*)(wr + 4);
            a00 = fmaf(xs0, w0.x, a00); a01 = fmaf(xs0, w0.y, a01);
            a02 = fmaf(xs0, w0.z, a02); a03 = fmaf(xs0, w0.w, a03);
            a04 = fmaf(xs0, w1.x, a04); a05 = fmaf(xs0, w1.y, a05);
            a06 = fmaf(xs0, w1.z, a06); a07 = fmaf(xs0, w1.w, a07);
            a10 = fmaf(xs1, w0.x, a10); a11 = fmaf(xs1, w0.y, a11);
            a12 = fmaf(xs1, w0.z, a12); a13 = fmaf(xs1, w0.w, a13);
            a14 = fmaf(xs1, w1.x, a14); a15 = fmaf(xs1, w1.y, a15);
            a16 = fmaf(xs1, w1.z, a16); a17 = fmaf(xs1, w1.w, a17);
        }
    }

    if (v0) {
        uint4 p;
        p.x = (unsigned)f2bf(a00) | ((unsigned)f2bf(a01) << 16);
        p.y = (unsigned)f2bf(a02) | ((unsigned)f2bf(a03) << 16);
        p.z = (unsigned)f2bf(a04) | ((unsigned)f2bf(a05) << 16);
        p.w = (unsigned)f2bf(a06) | ((unsigned)f2bf(a07) << 16);
        *(uint4*)&H[(size_t)r0 * 64 + c0] = p;
    }
    if (v1) {
        uint4 p;
        p.x = (unsigned)f2bf(a10) | ((unsigned)f2bf(a11) << 16);
        p.y = (unsigned)f2bf(a12) | ((unsigned)f2bf(a13) << 16);
        p.z = (unsigned)f2bf(a14) | ((unsigned)f2bf(a15) << 16);
        p.w = (unsigned)f2bf(a16) | ((unsigned)f2bf(a17) << 16);
        *(uint4*)&H[(size_t)r1 * 64 + c0] = p;
    }
}

// ---------------- Aggregation (bf16 H, GPW=2, R6-proven 4x16 lane layout) ----------------
// R8 lesson: wreg[64] tail requires launch_bounds(256,2) headroom — (256,6)
// spilled wreg to scratch (WRITE 6.25->150MB, 141us). R7 proved (256,2) holds
// it at VGPR=52 with zero spill.

template <bool RELU>
__device__ __forceinline__ float4 agg_node(const unsigned short* __restrict__ H,
                                           const long long* __restrict__ csr_ll,
                                           const float4& b4, float di,
                                           int i, int s, int e,
                                           int lane, int g, int c4) {
    float4 acc = make_float4(0.f, 0.f, 0.f, 0.f);

    for (int base = s; base < e; base += 64) {
        int eidx = base + lane;
        long long pk = (eidx < e) ? __builtin_nontemporal_load(csr_ll + eidx) : 0LL;
        int px = (int)(pk & 0xffffffffLL);
        int py = (int)(pk >> 32);                 // norm bits (0 -> 0.0f)
        int m  = e - base; if (m > 64) m = 64;
        int nt = (m + 3) >> 2;
#pragma unroll 4
        for (int t = 0; t < nt; ++t) {
            int sl   = t * 4 + g;
            int ss   = __shfl(px, sl);
            float nn = __uint_as_float(__shfl(py, sl));
            ushort4 h = *(const ushort4*)&H[(size_t)ss * 64 + c4];
            acc.x = fmaf(bf2f(h.x), nn, acc.x);
            acc.y = fmaf(bf2f(h.y), nn, acc.y);
            acc.z = fmaf(bf2f(h.z), nn, acc.z);
            acc.w = fmaf(bf2f(h.w), nn, acc.w);
        }
    }

#pragma unroll
    for (int d = 16; d <= 32; d <<= 1) {
        acc.x += __shfl_xor(acc.x, d);
        acc.y += __shfl_xor(acc.y, d);
        acc.z += __shfl_xor(acc.z, d);
        acc.w += __shfl_xor(acc.w, d);
    }

    float sl2 = 2.0f * di * di;
    ushort4 hs = *(const ushort4*)&H[(size_t)i * 64 + c4];
    float4 r;
    r.x = acc.x + sl2 * bf2f(hs.x) + b4.x;
    r.y = acc.y + sl2 * bf2f(hs.y) + b4.y;
    r.z = acc.z + sl2 * bf2f(hs.z) + b4.z;
    r.w = acc.w + sl2 * bf2f(hs.w) + b4.w;
    if (RELU) {
        r.x = fmaxf(r.x, 0.f); r.y = fmaxf(r.y, 0.f);
        r.z = fmaxf(r.z, 0.f); r.w = fmaxf(r.w, 0.f);
    }
    return r;
}

// Fused: A = ReLU(S*H + b) then y = A @ Wn per node; Hout bf16. No LDS.
__global__ __launch_bounds__(256, 2) void k_fused(const unsigned short* __restrict__ H,
                                                  const int* __restrict__ row_ptr,
                                                  const long long* __restrict__ csr_ll,
                                                  const float* __restrict__ dinv,
                                                  const float* __restrict__ bias,
                                                  const float* __restrict__ Wn,
                                                  unsigned short* __restrict__ Hout, int N) {
    const int lane = threadIdx.x & 63;
    const int wid  = threadIdx.x >> 6;
    const int i0   = (blockIdx.x * 4 + wid) * GPW;
    if (i0 >= N) return;
    const int g  = lane >> 4;
    const int c4 = (lane & 15) * 4;

    // W column `lane` in registers; (256,2) gives the allocator room (R7: VGPR=52)
    float wreg[64];
#pragma unroll
    for (int k = 0; k < 64; ++k) wreg[k] = Wn[k * 64 + lane];

    const float4 b4 = *(const float4*)&bias[c4];

    int idx = i0 + lane;
    int rp_l   = (lane <= GPW && idx <= NN) ? row_ptr[idx] : 0;
    float di_l = (lane <  GPW && idx <  NN) ? dinv[idx]    : 0.f;

#pragma unroll
    for (int j = 0; j < GPW; ++j) {
        int i = i0 + j;
        if (i >= N) break;
        int   s  = __shfl(rp_l, j);
        int   e  = __shfl(rp_l, j + 1);
        float di = __shfl(di_l, j);

        float4 r = agg_node<true>(H, csr_ll, b4, di, i, s, e, lane, g, c4);

        // tail GEMM: channel 4q+k lives in lane q; broadcast via const readlane
        float y = 0.0f;
#pragma unroll
        for (int q = 0; q < 16; ++q) {
            y = fmaf(rdlane_f(r.x, q), wreg[4 * q + 0], y);
            y = fmaf(rdlane_f(r.y, q), wreg[4 * q + 1], y);
            y = fmaf(rdlane_f(r.z, q), wreg[4 * q + 2], y);
            y = fmaf(rdlane_f(r.w, q), wreg[4 * q + 3], y);
        }
        Hout[(size_t)i * 64 + lane] = f2bf(y);
    }
}

// Final layer: aggregation only (no ReLU), fp32 out (d_out). No wreg -> (256,4).
__global__ __launch_bounds__(256, 4) void k_agg_last(const unsigned short* __restrict__ H,
                                                     const int* __restrict__ row_ptr,
                                                     const long long* __restrict__ csr_ll,
                                                     const float* __restrict__ dinv,
                                                     const float* __restrict__ bias,
                                                     float* __restrict__ out, int N) {
    const int lane = threadIdx.x & 63;
    const int wid  = threadIdx.x >> 6;
    const int i0   = (blockIdx.x * 4 + wid) * GPW;
    if (i0 >= N) return;
    const int g  = lane >> 4;
    const int c4 = (lane & 15) * 4;

    const float4 b4 = *(const float4*)&bias[c4];

    int idx = i0 + lane;
    int rp_l   = (lane <= GPW && idx <= NN) ? row_ptr[idx] : 0;
    float di_l = (lane <  GPW && idx <  NN) ? dinv[idx]    : 0.f;

#pragma unroll
    for (int j = 0; j < GPW; ++j) {
        int i = i0 + j;
        if (i >= N) break;
        int   s  = __shfl(rp_l, j);
        int   e  = __shfl(rp_l, j + 1);
        float di = __shfl(di_l, j);

        float4 r = agg_node<false>(H, csr_ll, b4, di, i, s, e, lane, g, c4);
        if (g == 0)
            *(float4*)&out[(size_t)i * 64 + c4] = r;
    }
}

// ---------------- launch ----------------

extern "C" void kernel_launch(void* const* d_in, const int* in_sizes, int n_in,
                              void* d_out, int out_size, void* d_ws, size_t ws_size,
                              hipStream_t stream) {
    (void)in_sizes; (void)n_in; (void)out_size; (void)ws_size;

    const float* x  = (const float*)d_in[0];
    const int*   ei = (const int*)d_in[1];
    const float* Wl[5] = {(const float*)d_in[2], (const float*)d_in[4], (const float*)d_in[6],
                          (const float*)d_in[8], (const float*)d_in[10]};
    const float* bl[5] = {(const float*)d_in[3], (const float*)d_in[5], (const float*)d_in[7],
                          (const float*)d_in[9], (const float*)d_in[11]};
    float* out = (float*)d_out;

    const int* src = ei;
    const int* dst = ei + NE;

    char* ws = (char*)d_ws;
    size_t off = 0;
    auto alloc = [&](size_t bytes) -> void* {
        void* p = ws + off;
        off += (bytes + 255) & ~(size_t)255;
        return p;
    };
    int*   cnt      = (int*)alloc(NN * 4);
    int*   row_ptr  = (int*)alloc((NN + 1) * 4);
    int*   cursor   = (int*)alloc(NN * 4);
    int*   bsum     = (int*)alloc(256 * 4);
    float* dinv     = (float*)alloc(NN * 4);
    int2*  csr      = (int2*)alloc((size_t)NE * 8);
    unsigned short* Hb  = (unsigned short*)alloc((size_t)NN * 64 * 2);
    unsigned short* Hb2 = (unsigned short*)alloc((size_t)NN * 64 * 2);

    hipMemsetAsync(cnt, 0, NN * 4, stream);
    hipMemsetAsync(cursor, 0, NN * 4, stream);

    int ebl = (NE + 255) / 256;
    int nbl = (NN + 255) / 256;
    k_count<<<ebl, 256, 0, stream>>>(dst, cnt, NE);
    k_dinv<<<nbl, 256, 0, stream>>>(cnt, dinv, NN);
    k_scanA<<<nbl, 256, 0, stream>>>(cnt, row_ptr, bsum, NN);
    k_scanB<<<1, 256, 0, stream>>>(bsum, nbl);
    k_scanC<<<nbl, 256, 0, stream>>>(row_ptr, bsum, NN, NE);
    k_fill<<<ebl, 256, 0, stream>>>(src, dst, dinv, row_ptr, cursor, csr, NE);

    const long long* csr_ll = (const long long*)csr;
    int gg = (NN + 63) / 64;
    int nwaves = (NN + GPW - 1) / GPW;           // 25000
    int ga = (nwaves + 3) / 4;                   // 6250 blocks

    // layer 1 GEMM (K=128) -> bf16 H
    k_gemm128<<<gg, 256, 0, stream>>>(x, Wl[0], Hb, NN);
    // fused: agg_t (+b_t, ReLU) then @W_{t+1} -> bf16 H
    k_fused<<<ga, 256, 0, stream>>>(Hb,  row_ptr, csr_ll, dinv, bl[0], Wl[1], Hb2, NN);
    k_fused<<<ga, 256, 0, stream>>>(Hb2, row_ptr, csr_ll, dinv, bl[1], Wl[2], Hb,  NN);
    k_fused<<<ga, 256, 0, stream>>>(Hb,  row_ptr, csr_ll, dinv, bl[2], Wl[3], Hb2, NN);
    k_fused<<<ga, 256, 0, stream>>>(Hb2, row_ptr, csr_ll, dinv, bl[3], Wl[4], Hb,  NN);
    // final aggregation (no ReLU) -> fp32 d_out
    k_agg_last<<<ga, 256, 0, stream>>>(Hb, row_ptr, csr_ll, dinv, bl[4], out, NN);
}